// Round 1
// 1071.146 us; speedup vs baseline: 1.0155x; 1.0155x over previous
//
#include <hip/hip_runtime.h>
#include <hip/hip_bf16.h>

typedef __bf16 bf16;
typedef __bf16 bf16x8 __attribute__((ext_vector_type(8)));
typedef float  f32x4  __attribute__((ext_vector_type(4)));

#define NB   4
#define NS   2048
#define NH   12
#define ND   64
#define NHID 768
#define NM   (NB*NS)   // 8192

// async global->LDS, 16B per lane. LDS dest = wave-uniform base + lane*16.
__device__ __forceinline__ void async_cp16(void* lds, const void* g) {
  __builtin_amdgcn_global_load_lds(
      (const __attribute__((address_space(1))) void*)g,
      (__attribute__((address_space(3))) void*)lds, 16, 0, 0);
}

__device__ __forceinline__ f32x4 mfma16(bf16x8 a, bf16x8 b, f32x4 c) {
  return __builtin_amdgcn_mfma_f32_16x16x32_bf16(a, b, c, 0, 0, 0);
}

// counted-drain + raw barrier (T3 minimum 2-phase sync point)
__device__ __forceinline__ void vm0_bar() {
  asm volatile("s_waitcnt vmcnt(0)" ::: "memory");
  __builtin_amdgcn_s_barrier();
}

// ---------------- converts ----------------
__global__ void k_cvt_x(const float4* __restrict__ x, bf16* __restrict__ o) {
  int i = blockIdx.x * 256 + threadIdx.x;
  float4 v = x[i];
  bf16* p = o + (size_t)i * 4;
  p[0] = (bf16)v.x; p[1] = (bf16)v.y; p[2] = (bf16)v.z; p[3] = (bf16)v.w;
}

// W [K=768][N=768] fp32 -> Wt [N][K] bf16 (NT layout for MFMA B^T reads)
__global__ void k_trans_w(const float* __restrict__ W0, const float* __restrict__ W1,
                          const float* __restrict__ W2, const float* __restrict__ W3,
                          bf16* __restrict__ T0, bf16* __restrict__ T1,
                          bf16* __restrict__ T2, bf16* __restrict__ T3) {
  int z = blockIdx.z;
  const float* W = (z==0)?W0:(z==1)?W1:(z==2)?W2:W3;
  bf16*        T = (z==0)?T0:(z==1)?T1:(z==2)?T2:T3;
  __shared__ float t[32][33];
  int tx = threadIdx.x & 31, ty = threadIdx.x >> 5;   // 8 rows per pass
  int n0 = blockIdx.x * 32, k0 = blockIdx.y * 32;
  for (int i = 0; i < 32; i += 8)
    t[ty + i][tx] = W[(size_t)(k0 + ty + i) * NHID + n0 + tx];
  __syncthreads();
  for (int i = 0; i < 32; i += 8)
    T[(size_t)(n0 + ty + i) * NHID + k0 + tx] = (bf16)t[tx][ty + i];
}

// ---------------- QKV projection: y = x @ W + b, scattered per-head ----------------
// 1D grid 1152, XCD-bijective decode: blocks sharing the same A-panel (m) land on
// the same XCD (flat%8 constant per m-panel). z=0 -> q, z=1 -> k, z=2 -> v^T.
__launch_bounds__(256, 2)
__global__ void k_proj(const bf16* __restrict__ xb,
                       const bf16* __restrict__ Wtq, const bf16* __restrict__ Wtk,
                       const bf16* __restrict__ Wtv,
                       const float* __restrict__ bq, const float* __restrict__ bk,
                       const float* __restrict__ bv,
                       bf16* __restrict__ qo, bf16* __restrict__ ko, bf16* __restrict__ vto) {
  const int id = blockIdx.x;
  const int kx = id & 7, sl = id >> 3;        // sl 0..143
  const int my = (sl / 18) * 8 + kx;          // m-panel 0..63 (same XCD for all 18 blocks)
  const int r2 = sl % 18;
  const int nx = r2 % 6, z = r2 / 6;
  const bf16*  Wt   = (z==0)?Wtq:(z==1)?Wtk:Wtv;
  const float* bias = (z==0)?bq :(z==1)?bk :bv;
  __shared__ __align__(16) bf16 As[2][128*32];
  __shared__ __align__(16) bf16 Bs[2][128*32];
  const int tid = threadIdx.x, w = tid >> 6, l = tid & 63;
  const int m0 = my * 128, n0 = nx * 128;

  // staging: slot p=i*256+tid -> row p>>2, phys chunk p&3, logical = phys ^ (row&3)
  const int lr = tid >> 2, lc = tid & 3;
  const bf16* agp[2]; const bf16* bgp[2];
  for (int i = 0; i < 2; i++) {
    int r = i * 64 + lr;
    int cl = lc ^ (r & 3);
    agp[i] = xb + (size_t)(m0 + r) * NHID + cl * 8;
    bgp[i] = Wt + (size_t)(n0 + r) * NHID + cl * 8;
  }
  auto stage = [&](int b, int kt) {
    const size_t ko2 = (size_t)kt * 32;
    for (int i = 0; i < 2; i++) {
      async_cp16((char*)As + b * 8192 + i * 4096 + w * 1024, agp[i] + ko2);
      async_cp16((char*)Bs + b * 8192 + i * 4096 + w * 1024, bgp[i] + ko2);
    }
  };
  // frag read offsets (swizzle makes chunk lane-constant)
  const int fch = ((l >> 4) ^ (l & 3)) * 8;
  const int wm = (w >> 1) * 64, wn = (w & 1) * 64;
  int aoff[4], boff[4];
  for (int i = 0; i < 4; i++) {
    aoff[i] = (wm + i * 16 + (l & 15)) * 32 + fch;
    boff[i] = (wn + i * 16 + (l & 15)) * 32 + fch;
  }
  f32x4 acc[4][4];
  f32x4 zf = {0.f, 0.f, 0.f, 0.f};
  for (int i = 0; i < 4; i++) for (int j = 0; j < 4; j++) acc[i][j] = zf;

  stage(0, 0);
  vm0_bar();
  for (int kt = 0; kt < NHID / 32; kt++) {
    const int cur = kt & 1;
    if (kt < NHID / 32 - 1) stage(cur ^ 1, kt + 1);   // prefetch flies under MFMA
    const bf16* Ab = &As[cur][0];
    const bf16* Bb = &Bs[cur][0];
    bf16x8 af[4], bfr[4];
    for (int i = 0; i < 4; i++) af[i]  = *(const bf16x8*)(Ab + aoff[i]);
    for (int i = 0; i < 4; i++) bfr[i] = *(const bf16x8*)(Bb + boff[i]);
    for (int i = 0; i < 4; i++)
      for (int j = 0; j < 4; j++)
        acc[i][j] = mfma16(af[i], bfr[j], acc[i][j]);
    vm0_bar();
  }
  bf16* outp = (z==0)?qo:(z==1)?ko:vto;
  for (int i = 0; i < 4; i++) {
    int mrow0 = m0 + wm + i * 16 + (l >> 4) * 4;
    for (int j = 0; j < 4; j++) {
      int col = n0 + wn + j * 16 + (l & 15);
      float bb = bias[col];
      int h = col >> 6, d = col & 63;
      for (int r = 0; r < 4; r++) {
        int m = mrow0 + r;
        int b = m >> 11, s = m & 2047;
        float v = acc[i][j][r] + bb;
        size_t idx;
        if (z < 2) idx = ((size_t)(b * NH + h) * NS + s) * ND + d;
        else       idx = ((size_t)(b * NH + h) * ND + d) * NS + s;
        outp[idx] = (bf16)v;
      }
    }
  }
}

// ---------------- pass 1: rowsum of exp(QK^T/8) ----------------
// 1D grid 768; bijective XCD decode keeps all 16 q-tiles of one head on one XCD.
// Q fragments loaded straight to registers; K double-buffered (32 KB LDS, 4 blk/CU).
__launch_bounds__(256, 4)
__global__ void k_rowsum(const bf16* __restrict__ qg, const bf16* __restrict__ kg,
                         float* __restrict__ rowsum) {
  const int L = blockIdx.x;
  const int bh = ((L >> 7) << 3) | (L & 7);   // head-batch 0..47, L%8 fixed per bh
  const int q0 = ((L >> 3) & 15) * 128;
  __shared__ __align__(16) bf16 Ks[2][128*64];
  const int tid = threadIdx.x, w = tid >> 6, l = tid & 63;
  const int lr8 = tid >> 3, lc8 = tid & 7;

  // Q fragments: lane l row (l&15), k-cols ks*32 + (l>>4)*8
  bf16x8 aq[2][2];
  for (int rb = 0; rb < 2; rb++)
    for (int ks = 0; ks < 2; ks++)
      aq[rb][ks] = *(const bf16x8*)(qg +
          ((size_t)bh * NS + q0 + w * 32 + rb * 16 + (l & 15)) * ND +
          ks * 32 + (l >> 4) * 8);

  int boff[8][2];
  for (int cb = 0; cb < 8; cb++)
    for (int ks = 0; ks < 2; ks++) {
      int row = cb * 16 + (l & 15);
      int ph = (ks * 4 + (l >> 4)) ^ (l & 7);
      boff[cb][ks] = row * 64 + ph * 8;
    }
  auto stageK = [&](int b, int kt) {
    const bf16* kbase = kg + ((size_t)bh * NS + kt * 128) * ND;
    for (int i = 0; i < 4; i++) {
      int r = i * 32 + lr8;
      int cl = lc8 ^ (r & 7);
      async_cp16((char*)Ks + b * 16384 + i * 4096 + w * 1024,
                 kbase + (size_t)r * ND + cl * 8);
    }
  };
  float rs[2][4];
  for (int rb = 0; rb < 2; rb++) for (int r = 0; r < 4; r++) rs[rb][r] = 0.f;

  stageK(0, 0);
  vm0_bar();
  for (int kt = 0; kt < NS / 128; kt++) {
    const int cur = kt & 1;
    if (kt < NS / 128 - 1) stageK(cur ^ 1, kt + 1);
    const bf16* Kb = &Ks[cur][0];
    for (int cb = 0; cb < 8; cb++) {
      bf16x8 b0 = *(const bf16x8*)(Kb + boff[cb][0]);
      bf16x8 b1 = *(const bf16x8*)(Kb + boff[cb][1]);
      for (int rb = 0; rb < 2; rb++) {
        f32x4 acc = {0.f, 0.f, 0.f, 0.f};
        __builtin_amdgcn_s_setprio(1);
        acc = mfma16(aq[rb][0], b0, acc);
        acc = mfma16(aq[rb][1], b1, acc);
        __builtin_amdgcn_s_setprio(0);
        for (int r = 0; r < 4; r++) rs[rb][r] += __expf(acc[r] * 0.125f);
      }
    }
    vm0_bar();
  }
  for (int m = 1; m < 16; m <<= 1)
    for (int rb = 0; rb < 2; rb++)
      for (int r = 0; r < 4; r++)
        rs[rb][r] += __shfl_xor(rs[rb][r], m, 64);
  if ((l & 15) == 0)
    for (int rb = 0; rb < 2; rb++)
      for (int r = 0; r < 4; r++)
        rowsum[(size_t)bh * NS + q0 + w * 32 + rb * 16 + (l >> 4) * 4 + r] = rs[rb][r];
}

// ---------------- pass 2: normalized attn write + PV ----------------
// Q + 1/rowsum in registers; K and V double-buffered (74 KB LDS, 2 blk/CU);
// stage(t+1) issued before compute(t), single vmcnt(0)+barrier per tile.
__launch_bounds__(256, 2)
__global__ void k_attn(const bf16* __restrict__ qg, const bf16* __restrict__ kg,
                       const bf16* __restrict__ vtg, const float* __restrict__ rowsum,
                       float* __restrict__ attn, bf16* __restrict__ ctxo) {
  const int L = blockIdx.x;
  const int bh = ((L >> 7) << 3) | (L & 7);
  const int q0 = ((L >> 3) & 15) * 128;
  __shared__ __align__(16) bf16 Ks[2][128*64];
  __shared__ __align__(16) bf16 Vs[2][64*128];
  __shared__ __align__(16) bf16 Ps[4][32*40];   // per-wave P chunk, pad 40 breaks conflicts
  const int tid = threadIdx.x, w = tid >> 6, l = tid & 63;
  const int lr8 = tid >> 3, lc8 = tid & 7;
  const int lr16 = tid >> 4, lc16 = tid & 15;

  // Q fragments + reciprocal rowsum straight to registers
  bf16x8 aq[2][2];
  float rv[2][4];
  for (int rb = 0; rb < 2; rb++) {
    for (int ks = 0; ks < 2; ks++)
      aq[rb][ks] = *(const bf16x8*)(qg +
          ((size_t)bh * NS + q0 + w * 32 + rb * 16 + (l & 15)) * ND +
          ks * 32 + (l >> 4) * 8);
    for (int r = 0; r < 4; r++)
      rv[rb][r] = 1.f / rowsum[(size_t)bh * NS + q0 + w * 32 + rb * 16 + (l >> 4) * 4 + r];
  }

  int boff[8][2];
  for (int cb = 0; cb < 8; cb++)
    for (int ks = 0; ks < 2; ks++) {
      int row = cb * 16 + (l & 15);
      int ph = (ks * 4 + (l >> 4)) ^ (l & 7);
      boff[cb][ks] = row * 64 + ph * 8;
    }
  auto stageK = [&](int b, int kt) {
    const bf16* kbase = kg + ((size_t)bh * NS + kt * 128) * ND;
    for (int i = 0; i < 4; i++) {
      int r = i * 32 + lr8;
      int cl = lc8 ^ (r & 7);
      async_cp16((char*)Ks + b * 16384 + i * 4096 + w * 1024,
                 kbase + (size_t)r * ND + cl * 8);
    }
  };
  auto stageV = [&](int b, int kt) {
    const bf16* vbase = vtg + (size_t)bh * ND * NS + (size_t)kt * 128;
    for (int i = 0; i < 4; i++) {
      int r = i * 16 + lr16;
      int cl = lc16 ^ (r & 15);
      async_cp16((char*)Vs + b * 16384 + i * 4096 + w * 1024,
                 vbase + (size_t)r * NS + cl * 8);
    }
  };
  f32x4 ctx[2][4];
  f32x4 zf = {0.f, 0.f, 0.f, 0.f};
  for (int i = 0; i < 2; i++) for (int j = 0; j < 4; j++) ctx[i][j] = zf;

  stageK(0, 0); stageV(0, 0);
  vm0_bar();
  const size_t arow0 = (size_t)bh * NS + q0 + w * 32;
  for (int kt = 0; kt < NS / 128; kt++) {
    const int cur = kt & 1;
    if (kt < NS / 128 - 1) { stageK(cur ^ 1, kt + 1); stageV(cur ^ 1, kt + 1); }
    const bf16* Kb = &Ks[cur][0];
    const bf16* Vb = &Vs[cur][0];
    for (int ks2 = 0; ks2 < 4; ks2++) {
      for (int cc = 0; cc < 2; cc++) {
        int cb = ks2 * 2 + cc;
        bf16x8 b0 = *(const bf16x8*)(Kb + boff[cb][0]);
        bf16x8 b1 = *(const bf16x8*)(Kb + boff[cb][1]);
        for (int rb = 0; rb < 2; rb++) {
          f32x4 acc = {0.f, 0.f, 0.f, 0.f};
          __builtin_amdgcn_s_setprio(1);
          acc = mfma16(aq[rb][0], b0, acc);
          acc = mfma16(aq[rb][1], b1, acc);
          __builtin_amdgcn_s_setprio(0);
          int rloc = rb * 16 + (l >> 4) * 4;
          for (int r = 0; r < 4; r++) {
            float p = __expf(acc[r] * 0.125f) * rv[rb][r];
            attn[(arow0 + rloc + r) * NS + (size_t)kt * 128 + cb * 16 + (l & 15)] = p;
            Ps[w][(rloc + r) * 40 + cc * 16 + (l & 15)] = (bf16)p;
          }
        }
      }
      // P (A-layout) x V^T (B^T layout) -> ctx ; per-wave LDS, no barrier needed
      bf16x8 pa[2];
      for (int rb = 0; rb < 2; rb++)
        pa[rb] = *(const bf16x8*)(&Ps[w][(rb * 16 + (l & 15)) * 40 + (l >> 4) * 8]);
      __builtin_amdgcn_s_setprio(1);
      for (int db = 0; db < 4; db++) {
        int dd = db * 16 + (l & 15);
        int ph = (ks2 * 4 + (l >> 4)) ^ (l & 15);
        bf16x8 vb = *(const bf16x8*)(Vb + dd * 128 + ph * 8);
        for (int rb = 0; rb < 2; rb++)
          ctx[rb][db] = mfma16(pa[rb], vb, ctx[rb][db]);
      }
      __builtin_amdgcn_s_setprio(0);
    }
    vm0_bar();
  }
  const int b = bh / NH, h = bh - b * NH;
  for (int rb = 0; rb < 2; rb++) {
    int qrow0 = q0 + w * 32 + rb * 16 + (l >> 4) * 4;
    for (int db = 0; db < 4; db++) {
      int dd = db * 16 + (l & 15);
      for (int r = 0; r < 4; r++)
        ctxo[((size_t)(b * NS + qrow0 + r)) * NHID + h * ND + dd] = (bf16)ctx[rb][db][r];
    }
  }
}

// ---------------- output projection: out = ctx @ Wo + bo (fp32 out) ----------------
// 1D grid 384 with XCD decode; pipelined like k_proj.
__launch_bounds__(256, 2)
__global__ void k_oproj(const bf16* __restrict__ cb_, const bf16* __restrict__ Wto,
                        const float* __restrict__ bo, float* __restrict__ out) {
  const int id = blockIdx.x;
  const int kx = id & 7, sl = id >> 3;        // sl 0..47
  const int my = (sl / 6) * 8 + kx;           // m-panel 0..63
  const int nx = sl % 6;
  __shared__ __align__(16) bf16 As[2][128*32];
  __shared__ __align__(16) bf16 Bs[2][128*32];
  const int tid = threadIdx.x, w = tid >> 6, l = tid & 63;
  const int m0 = my * 128, n0 = nx * 128;
  const int lr = tid >> 2, lc = tid & 3;
  const bf16* agp[2]; const bf16* bgp[2];
  for (int i = 0; i < 2; i++) {
    int r = i * 64 + lr;
    int cl = lc ^ (r & 3);
    agp[i] = cb_ + (size_t)(m0 + r) * NHID + cl * 8;
    bgp[i] = Wto + (size_t)(n0 + r) * NHID + cl * 8;
  }
  auto stage = [&](int b, int kt) {
    const size_t ko2 = (size_t)kt * 32;
    for (int i = 0; i < 2; i++) {
      async_cp16((char*)As + b * 8192 + i * 4096 + w * 1024, agp[i] + ko2);
      async_cp16((char*)Bs + b * 8192 + i * 4096 + w * 1024, bgp[i] + ko2);
    }
  };
  const int fch = ((l >> 4) ^ (l & 3)) * 8;
  const int wm = (w >> 1) * 64, wn = (w & 1) * 64;
  int aoff[4], boff[4];
  for (int i = 0; i < 4; i++) {
    aoff[i] = (wm + i * 16 + (l & 15)) * 32 + fch;
    boff[i] = (wn + i * 16 + (l & 15)) * 32 + fch;
  }
  f32x4 acc[4][4];
  f32x4 zf = {0.f, 0.f, 0.f, 0.f};
  for (int i = 0; i < 4; i++) for (int j = 0; j < 4; j++) acc[i][j] = zf;

  stage(0, 0);
  vm0_bar();
  for (int kt = 0; kt < NHID / 32; kt++) {
    const int cur = kt & 1;
    if (kt < NHID / 32 - 1) stage(cur ^ 1, kt + 1);
    const bf16* Ab = &As[cur][0];
    const bf16* Bb = &Bs[cur][0];
    bf16x8 af[4], bfr[4];
    for (int i = 0; i < 4; i++) af[i]  = *(const bf16x8*)(Ab + aoff[i]);
    for (int i = 0; i < 4; i++) bfr[i] = *(const bf16x8*)(Bb + boff[i]);
    for (int i = 0; i < 4; i++)
      for (int j = 0; j < 4; j++)
        acc[i][j] = mfma16(af[i], bfr[j], acc[i][j]);
    vm0_bar();
  }
  for (int i = 0; i < 4; i++) {
    int mrow0 = m0 + wm + i * 16 + (l >> 4) * 4;
    for (int j = 0; j < 4; j++) {
      int col = n0 + wn + j * 16 + (l & 15);
      float bb = bo[col];
      for (int r = 0; r < 4; r++)
        out[(size_t)(mrow0 + r) * NHID + col] = acc[i][j][r] + bb;
    }
  }
}

extern "C" void kernel_launch(void* const* d_in, const int* in_sizes, int n_in,
                              void* d_out, int out_size, void* d_ws, size_t ws_size,
                              hipStream_t stream) {
  const float* x  = (const float*)d_in[0];
  const float* Wq = (const float*)d_in[1];
  const float* bq = (const float*)d_in[2];
  const float* Wk = (const float*)d_in[3];
  const float* bk = (const float*)d_in[4];
  const float* Wv = (const float*)d_in[5];
  const float* bv = (const float*)d_in[6];
  const float* Wo = (const float*)d_in[7];
  const float* bo = (const float*)d_in[8];
  float* out  = (float*)d_out;
  float* attn = out + (size_t)NB * NS * NHID;

  char* ws = (char*)d_ws;
  const size_t XB = (size_t)NM * NHID * 2;          // 12,582,912
  const size_t WB = (size_t)NHID * NHID * 2;        //  1,179,648
  const size_t QB = (size_t)NB * NH * NS * ND * 2;  // 12,582,912
  bf16* xb  = (bf16*)(ws);
  bf16* Wtq = (bf16*)(ws + XB);
  bf16* Wtk = (bf16*)(ws + XB + WB);
  bf16* Wtv = (bf16*)(ws + XB + 2 * WB);
  bf16* Wto = (bf16*)(ws + XB + 3 * WB);
  bf16* qw  = (bf16*)(ws + XB + 4 * WB);
  bf16* kw  = (bf16*)(ws + XB + 4 * WB + QB);
  bf16* vtw = (bf16*)(ws + XB + 4 * WB + 2 * QB);
  bf16* ctx = (bf16*)(ws + XB + 4 * WB + 3 * QB);
  float* rsum = (float*)(ws + XB + 4 * WB + 4 * QB);

  hipLaunchKernelGGL(k_cvt_x, dim3(NM * NHID / 1024), dim3(256), 0, stream,
                     (const float4*)x, xb);
  hipLaunchKernelGGL(k_trans_w, dim3(24, 24, 4), dim3(256), 0, stream,
                     Wq, Wk, Wv, Wo, Wtq, Wtk, Wtv, Wto);
  hipLaunchKernelGGL(k_proj, dim3(1152), dim3(256), 0, stream,
                     xb, Wtq, Wtk, Wtv, bq, bk, bv, qw, kw, vtw);
  hipLaunchKernelGGL(k_rowsum, dim3(768), dim3(256), 0, stream,
                     qw, kw, rsum);
  hipLaunchKernelGGL(k_attn, dim3(768), dim3(256), 0, stream,
                     qw, kw, vtw, rsum, attn, ctx);
  hipLaunchKernelGGL(k_oproj, dim3(384), dim3(256), 0, stream,
                     ctx, Wto, bo, out);
}